// Round 14
// baseline (101.234 us; speedup 1.0000x reference)
//
#include <hip/hip_runtime.h>

#define NTH 21
#define NBIN 22               // delta bins k in [0,21]; 21 = never-certain
#define NROWS (2 * NBIN + 2)  // 22 n-bins + 22 d-bins + Snu + Sdu = 46
#define NBLK 256              // 1 block/CU (R11: fewer blocks won)
#define THREADS 256
#define PSTRIDE 45            // private bins stride (44 bins + 1 pad, bank spread)
#define EPSF 1e-10f

// ws layout (floats):
//   [PAIRS_OFF_F ..] : float2 pairs[NBLK]          (per-block {min,max} from K1)
//   [PART_OFF_F ..]  : float partials[NROWS][NBLK] (transposed, from K2)
// Coherence purely via kernel boundaries (no fences: R6 = +115us L2 writebacks;
// no global atomics: R8 = +11us tail).
// Accumulation: PER-THREAD private LDS delta bins (ds_add_f32, zero same-address
// contention -- R9's shared-bin atomics serialized ~3-way and regressed).
#define PAIRS_OFF_F 16
#define PART_OFF_F 2560

static __device__ __forceinline__ float bcast_f(float v) {
  // wave-uniform broadcast -> forces SGPR allocation
  return __uint_as_float(__builtin_amdgcn_readfirstlane(__float_as_uint(v)));
}

__global__ void __launch_bounds__(THREADS) minmax_kernel(
    const float4* __restrict__ unc4, float* __restrict__ ws, int n4) {
  float lmin = 1e30f, lmax = -1e30f;
  int stride = gridDim.x * blockDim.x;
  for (int i = blockIdx.x * blockDim.x + threadIdx.x; i < n4; i += stride) {
    float4 v = unc4[i];
    lmin = fminf(lmin, fminf(fminf(v.x, v.y), fminf(v.z, v.w)));
    lmax = fmaxf(lmax, fmaxf(fmaxf(v.x, v.y), fmaxf(v.z, v.w)));
  }
  #pragma unroll
  for (int off = 32; off > 0; off >>= 1) {
    lmin = fminf(lmin, __shfl_down(lmin, off));
    lmax = fmaxf(lmax, __shfl_down(lmax, off));
  }
  __shared__ float smin[4], smax[4];
  int wv = threadIdx.x >> 6;
  if ((threadIdx.x & 63) == 0) { smin[wv] = lmin; smax[wv] = lmax; }
  __syncthreads();
  if (threadIdx.x == 0) {
    float bmin = fminf(fminf(smin[0], smin[1]), fminf(smin[2], smin[3]));
    float bmax = fmaxf(fmaxf(smax[0], smax[1]), fmaxf(smax[2], smax[3]));
    ((float2*)(ws + PAIRS_OFF_F))[blockIdx.x] = make_float2(bmin, bmax);
  }
}

__global__ void __launch_bounds__(THREADS) main_kernel(
    const float4* __restrict__ probs4,
    const int4* __restrict__ labels4,
    const float4* __restrict__ unc4,
    float* __restrict__ ws, int n4) {
  const int t = threadIdx.x;
  const int b = blockIdx.x;
  const int lane = t & 63, wv = t >> 6;

  __shared__ float priv[THREADS * PSTRIDE];   // 45KB: per-thread delta bins
  __shared__ float smin[4], smax[4];
  __shared__ float bc[2];
  __shared__ float redc[2 * NBIN][4];
  __shared__ float lsum[4][2];

  // zero private bins
  for (int i = t; i < THREADS * PSTRIDE; i += THREADS) priv[i] = 0.f;

  // ---- preamble: reduce NBLK pairs (one float2 per thread; 2KB) ----
  {
    float2 v = ((const float2*)(ws + PAIRS_OFF_F))[t];  // t < NBLK == THREADS
    float gmin = v.x, gmax = v.y;
    #pragma unroll
    for (int off = 32; off > 0; off >>= 1) {
      gmin = fminf(gmin, __shfl_down(gmin, off));
      gmax = fmaxf(gmax, __shfl_down(gmax, off));
    }
    if (lane == 0) { smin[wv] = gmin; smax[wv] = gmax; }
    __syncthreads();
    if (t == 0) {
      bc[0] = fminf(fminf(smin[0], smin[1]), fminf(smin[2], smin[3]));
      bc[1] = fmaxf(fmaxf(smax[0], smax[1]), fmaxf(smax[2], smax[3]));
    }
    __syncthreads();
  }
  const float umin = bcast_f(bc[0]);
  const float r = bcast_f(bc[1]) - umin;
  // k = #{j: u > umin + (j/20)*r} = clamp(ceil(20*(u-umin)/r), 0, 21)  (R9-verified)
  const float s20 = bcast_f((r > 0.f) ? (20.0f / r) : 0.0f);

  float* mybin = &priv[t * PSTRIDE];
  float Snu = 0.f, Sdu = 0.f;

  int stride = NBLK * THREADS;
  for (int i4 = b * THREADS + t; i4 < n4; i4 += stride) {
    float4 u4 = unc4[i4];
    float4 pA = probs4[2 * (size_t)i4];
    float4 pB = probs4[2 * (size_t)i4 + 1];
    int4 lb = labels4[i4];
    float us[4] = {u4.x, u4.y, u4.z, u4.w};
    float pxs[4] = {pA.x, pA.z, pB.x, pB.z};
    float pys[4] = {pA.y, pA.w, pB.y, pB.w};
    int labs[4] = {lb.x, lb.y, lb.z, lb.w};
    #pragma unroll
    for (int e = 0; e < 4; ++e) {
      float u = us[e];
      float conf = pys[e];
      int pred = (pys[e] > pxs[e]) ? 1 : 0;   // argmax: index 0 wins ties
      bool accb = (labs[e] == pred);
      float ex = __expf(2.0f * u);
      float tt = 1.0f - 2.0f / (1.0f + ex);   // tanh(u)
      float w1 = accb ? conf : (1.0f - conf);
      float du_ = w1 * tt;                    // uncertain-side weight
      float dc = w1 - du_;                    // certain-side weight
      float dd = dc - du_;                    // den delta when certain
      float dn = accb ? dc : -du_;            // num delta when certain
      float nu = accb ? 0.f : du_;            // num base (uncertain)
      Snu += nu;
      Sdu += du_;
      int k = (int)ceilf((u - umin) * s20);
      k = min(NTH, max(0, k));
      atomicAdd(&mybin[k], dn);               // ds_add_f32, private -> no contention
      atomicAdd(&mybin[NBIN + k], dd);
    }
  }
  __syncthreads();

  // ---- reduce 256 private copies -> 44 delta rows (44 rows x 4 chunks of 64) ----
  if (t < 2 * NBIN * 4) {
    int row = t >> 2, ch = t & 3;
    float s = 0.f;
    #pragma unroll 8
    for (int m = 0; m < 64; ++m)
      s += priv[(ch * 64 + m) * PSTRIDE + row];
    redc[row][ch] = s;
  }
  // Snu/Sdu: shfl-reduce per wave
  {
    float x = Snu, y = Sdu;
    #pragma unroll
    for (int off = 32; off > 0; off >>= 1) {
      x += __shfl_down(x, off);
      y += __shfl_down(y, off);
    }
    if (lane == 0) { lsum[wv][0] = x; lsum[wv][1] = y; }
  }
  __syncthreads();

  float* partials = ws + PART_OFF_F;
  if (t < 2 * NBIN) {
    float s = redc[t][0] + redc[t][1] + redc[t][2] + redc[t][3];
    partials[(size_t)t * NBLK + b] = s;
  } else if (t < 2 * NBIN + 2) {
    int q = t - 2 * NBIN;
    float s = lsum[0][q] + lsum[1][q] + lsum[2][q] + lsum[3][q];
    partials[(size_t)t * NBLK + b] = s;
  }
}

// one block: 46 rows x 16 chunks = 736 threads; each sums 16 floats (4 float4)
__global__ void final_kernel(const float* __restrict__ ws,
                             float* __restrict__ out) {
  const float* partials = ws + PART_OFF_F;
  __shared__ float lds[NROWS][16];
  __shared__ float hh[NROWS];
  int t = threadIdx.x;
  if (t < NROWS * 16) {
    int row = t >> 4, ch = t & 15;
    const float4* p4 = (const float4*)(partials + (size_t)row * NBLK + ch * 16);
    float s = 0.f;
    #pragma unroll
    for (int m = 0; m < 4; ++m) {
      float4 v = p4[m];
      s += (v.x + v.y) + (v.z + v.w);
    }
    lds[row][ch] = s;
  }
  __syncthreads();
  if (t < NROWS) {
    float s = 0.f;
    #pragma unroll
    for (int c = 0; c < 16; ++c) s += lds[t][c];
    hh[t] = s;
  }
  __syncthreads();
  if (t == 0) {
    // hh[0..21] n-delta bins, hh[22..43] d-delta bins, hh[44]=Snu, hh[45]=Sdu
    float SnuT = hh[2 * NBIN], SduT = hh[2 * NBIN + 1];
    float cumn = 0.f, cumd = 0.f;
    float auc = 0.f, prev = 0.f;
    #pragma unroll
    for (int j = 0; j < NTH; ++j) {
      cumn += hh[j];            // accn[j] = prefix sum of delta bins
      cumd += hh[NBIN + j];
      float avu = (SnuT + cumn) / (SduT + cumd + EPSF);
      if (j > 0) auc += 0.5f * (avu + prev) * 0.05f;
      prev = avu;
    }
    out[0] = -logf(auc + EPSF);   // BETA = 1
    out[1] = auc;
  }
}

extern "C" void kernel_launch(void* const* d_in, const int* in_sizes, int n_in,
                              void* d_out, int out_size, void* d_ws, size_t ws_size,
                              hipStream_t stream) {
  const float4* probs4 = (const float4*)d_in[0];
  const int4* labels4 = (const int4*)d_in[1];
  const float4* unc4 = (const float4*)d_in[2];
  float* wsf = (float*)d_ws;
  int n4 = in_sizes[2] / 4;

  minmax_kernel<<<NBLK, THREADS, 0, stream>>>(unc4, wsf, n4);
  main_kernel<<<NBLK, THREADS, 0, stream>>>(probs4, labels4, unc4, wsf, n4);
  final_kernel<<<1, NROWS * 16, 0, stream>>>(wsf, (float*)d_out);
}

// Round 15
// 93.319 us; speedup vs baseline: 1.0848x; 1.0848x over previous
//
#include <hip/hip_runtime.h>

#define NTH 21
#define NROWS (2 * NTH + 2)   // 42 threshold accumulators + Snu + Sdu = 44
#define NBLK 256              // 1 block/CU: best-measured config (R11, 93.7us)
#define THREADS 256
#define EPSF 1e-10f

// ws layout (floats):
//   [PAIRS_OFF_F ..] : float2 pairs[NBLK]          (per-block {min,max} from K1)
//   [TH_OFF_F ..]    : float th[NTH]               (from K2)
//   [PART_OFF_F ..]  : float partials[NROWS][NBLK] (transposed, from K3)
// Coherence purely via kernel boundaries (no fences: R6 = +115us of L2
// writebacks; no global atomics: R8 = +11us tail; no LDS atomics: R9/R14
// regressed vs register accumulators).
#define PAIRS_OFF_F 16
#define TH_OFF_F 1024
#define PART_OFF_F 2560

static __device__ __forceinline__ float bcast_f(float v) {
  // wave-uniform broadcast -> forces SGPR allocation for thresholds
  // (without this, th[21] lands in VGPRs and the 42 accumulators spill: R5)
  return __uint_as_float(__builtin_amdgcn_readfirstlane(__float_as_uint(v)));
}

__global__ void __launch_bounds__(THREADS) minmax_kernel(
    const float4* __restrict__ unc4, float* __restrict__ ws, int n4) {
  float lmin = 1e30f, lmax = -1e30f;
  int stride = gridDim.x * blockDim.x;
  for (int i = blockIdx.x * blockDim.x + threadIdx.x; i < n4; i += stride) {
    float4 v = unc4[i];
    lmin = fminf(lmin, fminf(fminf(v.x, v.y), fminf(v.z, v.w)));
    lmax = fmaxf(lmax, fmaxf(fmaxf(v.x, v.y), fmaxf(v.z, v.w)));
  }
  #pragma unroll
  for (int off = 32; off > 0; off >>= 1) {
    lmin = fminf(lmin, __shfl_down(lmin, off));
    lmax = fmaxf(lmax, __shfl_down(lmax, off));
  }
  __shared__ float smin[4], smax[4];
  int wv = threadIdx.x >> 6;
  if ((threadIdx.x & 63) == 0) { smin[wv] = lmin; smax[wv] = lmax; }
  __syncthreads();
  if (threadIdx.x == 0) {
    float bmin = fminf(fminf(smin[0], smin[1]), fminf(smin[2], smin[3]));
    float bmax = fmaxf(fmaxf(smax[0], smax[1]), fmaxf(smax[2], smax[3]));
    ((float2*)(ws + PAIRS_OFF_F))[blockIdx.x] = make_float2(bmin, bmax);
  }
}

// 1 block: reduce NBLK pairs -> publish th[21]
__global__ void __launch_bounds__(THREADS) thresh_kernel(float* __restrict__ ws) {
  int t = threadIdx.x;
  float2 v = ((const float2*)(ws + PAIRS_OFF_F))[t];  // t < NBLK == THREADS
  float gmin = v.x, gmax = v.y;
  #pragma unroll
  for (int off = 32; off > 0; off >>= 1) {
    gmin = fminf(gmin, __shfl_down(gmin, off));
    gmax = fmaxf(gmax, __shfl_down(gmax, off));
  }
  __shared__ float smin[4], smax[4];
  int wv = t >> 6;
  if ((t & 63) == 0) { smin[wv] = gmin; smax[wv] = gmax; }
  __syncthreads();
  if (t == 0) {
    float umin = fminf(fminf(smin[0], smin[1]), fminf(smin[2], smin[3]));
    float umax = fmaxf(fmaxf(smax[0], smax[1]), fmaxf(smax[2], smax[3]));
    float r = umax - umin;
    #pragma unroll
    for (int j = 0; j < NTH; ++j)
      ws[TH_OFF_F + j] = umin + ((float)j * 0.05f) * r;
  }
}

__global__ void __launch_bounds__(THREADS) main_kernel(
    const float4* __restrict__ probs4,
    const int4* __restrict__ labels4,
    const float4* __restrict__ unc4,
    float* __restrict__ ws, int n4) {
  const int t = threadIdx.x;
  const int b = blockIdx.x;
  const int lane = t & 63, wv = t >> 6;

  __shared__ float lred[4][NROWS];

  // thresholds: same-address broadcast load, then force into SGPRs
  float th[NTH];
  #pragma unroll
  for (int j = 0; j < NTH; ++j) th[j] = bcast_f(ws[TH_OFF_F + j]);

  float accn[NTH], accd[NTH];
  #pragma unroll
  for (int j = 0; j < NTH; ++j) { accn[j] = 0.f; accd[j] = 0.f; }
  float Snu = 0.f, Sdu = 0.f;

  int stride = NBLK * THREADS;
  for (int i4 = b * THREADS + t; i4 < n4; i4 += stride) {
    float4 u4 = unc4[i4];
    float4 pA = probs4[2 * (size_t)i4];
    float4 pB = probs4[2 * (size_t)i4 + 1];
    int4 lb = labels4[i4];
    float us[4] = {u4.x, u4.y, u4.z, u4.w};
    float pxs[4] = {pA.x, pA.z, pB.x, pB.z};
    float pys[4] = {pA.y, pA.w, pB.y, pB.w};
    int labs[4] = {lb.x, lb.y, lb.z, lb.w};
    #pragma unroll
    for (int e = 0; e < 4; ++e) {
      float u = us[e];
      float conf = pys[e];
      int pred = (pys[e] > pxs[e]) ? 1 : 0;   // argmax: index 0 wins ties
      bool accb = (labs[e] == pred);
      float ex = __expf(2.0f * u);
      float tt = 1.0f - 2.0f / (1.0f + ex);   // tanh(u)
      float w1 = accb ? conf : (1.0f - conf);
      float du_ = w1 * tt;                    // uncertain-side weight
      float dc = w1 - du_;                    // certain-side weight
      float dd = dc - du_;                    // den delta when certain
      float dn = accb ? dc : -du_;            // num delta when certain
      float nu = accb ? 0.f : du_;            // num base (uncertain)
      Snu += nu;
      Sdu += du_;
      #pragma unroll
      for (int j = 0; j < NTH; ++j) {
        float cf = (u <= th[j]) ? 1.0f : 0.0f;
        accn[j] += cf * dn;
        accd[j] += cf * dd;
      }
    }
  }

  // ---- block combine: shfl + LDS, write transposed partials ----
  float* partials = ws + PART_OFF_F;
  #pragma unroll
  for (int v = 0; v < NTH; ++v) {
    float x = accn[v], y = accd[v];
    #pragma unroll
    for (int off = 32; off > 0; off >>= 1) {
      x += __shfl_down(x, off);
      y += __shfl_down(y, off);
    }
    if (lane == 0) { lred[wv][v] = x; lred[wv][NTH + v] = y; }
  }
  {
    float x = Snu, y = Sdu;
    #pragma unroll
    for (int off = 32; off > 0; off >>= 1) {
      x += __shfl_down(x, off);
      y += __shfl_down(y, off);
    }
    if (lane == 0) { lred[wv][2 * NTH] = x; lred[wv][2 * NTH + 1] = y; }
  }
  __syncthreads();
  if (t < NROWS) {
    float s = lred[0][t] + lred[1][t] + lred[2][t] + lred[3][t];
    partials[(size_t)t * NBLK + b] = s;
  }
}

// one block: 44 rows x 16 chunks = 704 threads; each sums 16 floats (4 float4)
__global__ void final_kernel(const float* __restrict__ ws,
                             float* __restrict__ out) {
  const float* partials = ws + PART_OFF_F;
  __shared__ float lds[NROWS][16];
  __shared__ float hh[NROWS];
  int t = threadIdx.x;
  if (t < NROWS * 16) {
    int row = t >> 4, ch = t & 15;
    const float4* p4 = (const float4*)(partials + (size_t)row * NBLK + ch * 16);
    float s = 0.f;
    #pragma unroll
    for (int m = 0; m < 4; ++m) {
      float4 v = p4[m];
      s += (v.x + v.y) + (v.z + v.w);
    }
    lds[row][ch] = s;
  }
  __syncthreads();
  if (t < NROWS) {
    float s = 0.f;
    #pragma unroll
    for (int c = 0; c < 16; ++c) s += lds[t][c];
    hh[t] = s;
  }
  __syncthreads();
  if (t == 0) {
    float SnuT = hh[2 * NTH], SduT = hh[2 * NTH + 1];
    float auc = 0.f, prev = 0.f;
    #pragma unroll
    for (int j = 0; j < NTH; ++j) {
      float num = SnuT + hh[j];
      float den = SduT + hh[NTH + j];
      float avu = num / (den + EPSF);
      if (j > 0) auc += 0.5f * (avu + prev) * 0.05f;
      prev = avu;
    }
    out[0] = -logf(auc + EPSF);   // BETA = 1
    out[1] = auc;
  }
}

extern "C" void kernel_launch(void* const* d_in, const int* in_sizes, int n_in,
                              void* d_out, int out_size, void* d_ws, size_t ws_size,
                              hipStream_t stream) {
  const float4* probs4 = (const float4*)d_in[0];
  const int4* labels4 = (const int4*)d_in[1];
  const float4* unc4 = (const float4*)d_in[2];
  float* wsf = (float*)d_ws;
  int n4 = in_sizes[2] / 4;

  minmax_kernel<<<NBLK, THREADS, 0, stream>>>(unc4, wsf, n4);
  thresh_kernel<<<1, THREADS, 0, stream>>>(wsf);
  main_kernel<<<NBLK, THREADS, 0, stream>>>(probs4, labels4, unc4, wsf, n4);
  final_kernel<<<1, NROWS * 16, 0, stream>>>(wsf, (float*)d_out);
}